// Round 10
// baseline (324.821 us; speedup 1.0000x reference)
//
#include <hip/hip_runtime.h>

#define N_NODES 100000
#define N_EDGES 1600000
#define DIM 128
#define ACT 512
#define NG 64
#define CHUNK 128
#define NBUK 782            // ceil(N_NODES/CHUNK)
#define EB 4096             // edges per partition block
#define NBLK_E 391          // ceil(N_EDGES/EB)
#define NW 4                // waves per zgemm block

// ---------------- chunk-granular edge partition, dst side only ----------------

__global__ __launch_bounds__(256) void k_histA(const int* __restrict__ dst,
                                               int* __restrict__ hist) {
    __shared__ int lh[NBUK];
    int t = threadIdx.x;
    for (int i = t; i < NBUK; i += 256) lh[i] = 0;
    __syncthreads();
    int e0 = blockIdx.x * EB;
    int e1 = min(e0 + EB, N_EDGES);
    for (int i = e0 + t; i < e1; i += 256) atomicAdd(&lh[dst[i] >> 7], 1);
    __syncthreads();
    int* row = hist + (size_t)blockIdx.x * NBUK;
    for (int i = t; i < NBUK; i += 256) row[i] = lh[i];
}

// per-bucket column scan over blocks
__global__ __launch_bounds__(512) void k_bscanA(int* __restrict__ hist,
                                                int* __restrict__ colsum) {
    __shared__ int s[512];
    int b = blockIdx.x, t = threadIdx.x;
    int v = (t < NBLK_E) ? hist[(size_t)t * NBUK + b] : 0;
    s[t] = v;
    __syncthreads();
    for (int off = 1; off < 512; off <<= 1) {
        int add = (t >= off) ? s[t - off] : 0;
        __syncthreads();
        s[t] += add;
        __syncthreads();
    }
    if (t < NBLK_E) hist[(size_t)t * NBUK + b] = s[t] - v;
    if (t == 511) colsum[b] = s[511];
}

// scan bucket totals -> off_d
__global__ __launch_bounds__(1024) void k_bscanB(const int* __restrict__ colsum,
                                                 int* __restrict__ off_d) {
    __shared__ int s[1024];
    int t = threadIdx.x;
    int v = (t < NBUK) ? colsum[t] : 0;
    s[t] = v;
    __syncthreads();
    for (int off = 1; off < 1024; off <<= 1) {
        int add = (t >= off) ? s[t - off] : 0;
        __syncthreads();
        s[t] += add;
        __syncthreads();
    }
    if (t < NBUK) off_d[t] = s[t] - v;
    if (t == 1023) off_d[NBUK] = s[1023];
}

__global__ void k_bscanC(int* __restrict__ hist, const int* __restrict__ off_d) {
    int id = blockIdx.x * blockDim.x + threadIdx.x;
    if (id >= NBLK_E * NBUK) return;
    hist[id] += off_d[id % NBUK];
}

// partition fill: payload (dlocal7<<17)|src17
__global__ __launch_bounds__(256) void k_bfill(const int* __restrict__ src,
                                               const int* __restrict__ dst,
                                               const int* __restrict__ hist,
                                               int* __restrict__ edata_d) {
    __shared__ int cur[NBUK];
    int t = threadIdx.x;
    const int* row = hist + (size_t)blockIdx.x * NBUK;
    for (int i = t; i < NBUK; i += 256) cur[i] = row[i];
    __syncthreads();
    int e0 = blockIdx.x * EB;
    int e1 = min(e0 + EB, N_EDGES);
    for (int i = e0 + t; i < e1; i += 256) {
        int s = src[i], d = dst[i];
        int pd = atomicAdd(&cur[d >> 7], 1);
        edata_d[pd] = ((d & 127) << 17) | s;
    }
}

// ---------------- per-chunk in-degree -> dis, xd ----------------

__global__ __launch_bounds__(256) void k_indeg(const int* __restrict__ edata_d,
                                               const int* __restrict__ off_d,
                                               const float* __restrict__ x,
                                               float* __restrict__ dis,
                                               float4* __restrict__ xd) {
    __shared__ int cnt[CHUNK];
    int t = threadIdx.x;
    int b = blockIdx.x;
    if (t < CHUNK) cnt[t] = 0;
    __syncthreads();
    int e0 = off_d[b], e1 = off_d[b + 1];
    for (int i = e0 + t; i < e1; i += 256) atomicAdd(&cnt[edata_d[i] >> 17], 1);
    __syncthreads();
    if (t < CHUNK) {
        int node = b * CHUNK + t;
        if (node < N_NODES) {
            float d = rsqrtf((float)(cnt[t] + 1));
            dis[node] = d;
            float4 p;
            p.x = x[node * 3 + 0] * d;
            p.y = x[node * 3 + 1] * d;
            p.z = x[node * 3 + 2] * d;
            p.w = d;
            xd[node] = p;
        }
    }
}

// ---------------- layer-1 aggregation per dst chunk; agg.w = dis ----------------

__global__ __launch_bounds__(256) void k_agg(const int* __restrict__ edata_d,
                                             const int* __restrict__ off_d,
                                             const float4* __restrict__ xd,
                                             float4* __restrict__ agg) {
    __shared__ float ax[CHUNK], ay[CHUNK], az[CHUNK];
    int t = threadIdx.x;
    int b = blockIdx.x;
    if (t < CHUNK) { ax[t] = 0.f; ay[t] = 0.f; az[t] = 0.f; }
    __syncthreads();
    int e0 = off_d[b], e1 = off_d[b + 1];
    for (int i = e0 + t; i < e1; i += 256) {
        int p = edata_d[i];
        int dl = p >> 17;
        int s = p & 0x1FFFF;
        float4 y = xd[s];
        atomicAdd(&ax[dl], y.x);
        atomicAdd(&ay[dl], y.y);
        atomicAdd(&az[dl], y.z);
    }
    __syncthreads();
    if (t < CHUNK) {
        int node = b * CHUNK + t;
        if (node < N_NODES) {
            float4 self = xd[node];
            float d = self.w;
            float4 o;
            o.x = (ax[t] + self.x) * d;
            o.y = (ay[t] + self.y) * d;
            o.z = (az[t] + self.z) * d;
            o.w = d;                       // carry dis for zgemm
            agg[node] = o;
        }
    }
}

// ---------------- z contraction over dst chunks (register accumulators) ----------------
// z[g][n] = sum_edges(s->d) dis_d*dis_s*u_s[n] for g=batch[d]  +  sum_i dis_i^2*u_i[n] for g=batch[i]
// u_s[n] = relu(agg_s @ W1[:,n] + b1[n]) recomputed in-register. batch sorted ->
// a dst chunk spans [glo,ghi], almost always 1-2 graphs; windows of 4 rows in VGPRs.

#define EDGE_BODY(gv, Av, wv)                                                     \
    if ((gv) >= gw && (gv) < gw + 4) {                                            \
        float u0 = fmaxf(fmaf(Av.x, wa0, fmaf(Av.y, wa1, fmaf(Av.z, wa2, ba))), 0.f); \
        float u1 = fmaxf(fmaf(Av.x, wb0, fmaf(Av.y, wb1, fmaf(Av.z, wb2, bb))), 0.f); \
        int r = (gv) - gw;                                                        \
        if (r == 0)      { a00 = fmaf(wv, u0, a00); a01 = fmaf(wv, u1, a01); }    \
        else if (r == 1) { a10 = fmaf(wv, u0, a10); a11 = fmaf(wv, u1, a11); }    \
        else if (r == 2) { a20 = fmaf(wv, u0, a20); a21 = fmaf(wv, u1, a21); }    \
        else             { a30 = fmaf(wv, u0, a30); a31 = fmaf(wv, u1, a31); }    \
    }

__global__ __launch_bounds__(256) void k_zgemm(const float4* __restrict__ agg,
                                               const int* __restrict__ edata_d,
                                               const int* __restrict__ off_d,
                                               const int* __restrict__ batch,
                                               const float* __restrict__ dis,
                                               const float* __restrict__ W1,
                                               const float* __restrict__ b1,
                                               float* __restrict__ z) {
    __shared__ float accs[NW][4][DIM];   // 8 KB
    __shared__ float dsl[CHUNK];
    __shared__ int bat[CHUNK];
    int t = threadIdx.x;
    int wave = t >> 6, lane = t & 63;
    int b = blockIdx.x;
    int base = b * CHUNK;
    if (t < CHUNK) {
        int node = base + t;
        if (node < N_NODES) { dsl[t] = dis[node]; bat[t] = batch[node]; }
        else { dsl[t] = 0.f; bat[t] = NG; }
    }
    __syncthreads();
    int nlast = min(CHUNK - 1, N_NODES - 1 - base);
    int glo = bat[0];
    int ghi = bat[nlast];
    int n0 = lane * 2, n1 = n0 + 1;
    float wa0 = W1[n0], wa1 = W1[DIM + n0], wa2 = W1[2 * DIM + n0], ba = b1[n0];
    float wb0 = W1[n1], wb1 = W1[DIM + n1], wb2 = W1[2 * DIM + n1], bb = b1[n1];
    int e0 = off_d[b], e1 = off_d[b + 1];

    for (int gw = glo; gw <= ghi; gw += 4) {
        float a00 = 0.f, a01 = 0.f, a10 = 0.f, a11 = 0.f;
        float a20 = 0.f, a21 = 0.f, a30 = 0.f, a31 = 0.f;
        int i = e0 + wave;
        // x4 unrolled edge loop: 4 independent uniform agg loads in flight
        for (; i + 3 * NW < e1; i += 4 * NW) {
            int p0 = edata_d[i];
            int p1 = edata_d[i + NW];
            int p2 = edata_d[i + 2 * NW];
            int p3 = edata_d[i + 3 * NW];
            float4 A0 = agg[p0 & 0x1FFFF];
            float4 A1 = agg[p1 & 0x1FFFF];
            float4 A2 = agg[p2 & 0x1FFFF];
            float4 A3 = agg[p3 & 0x1FFFF];
            int g0 = bat[p0 >> 17], g1 = bat[p1 >> 17];
            int g2 = bat[p2 >> 17], g3 = bat[p3 >> 17];
            float w0 = dsl[p0 >> 17] * A0.w;
            float w1 = dsl[p1 >> 17] * A1.w;
            float w2 = dsl[p2 >> 17] * A2.w;
            float w3 = dsl[p3 >> 17] * A3.w;
            EDGE_BODY(g0, A0, w0)
            EDGE_BODY(g1, A1, w1)
            EDGE_BODY(g2, A2, w2)
            EDGE_BODY(g3, A3, w3)
        }
        for (; i < e1; i += NW) {
            int p = edata_d[i];
            float4 A = agg[p & 0x1FFFF];
            int g = bat[p >> 17];
            float w = dsl[p >> 17] * A.w;
            EDGE_BODY(g, A, w)
        }
        // self terms
        for (int ii = wave; ii <= nlast; ii += NW) {
            int g = bat[ii];
            if (g >= gw && g < gw + 4) {
                float4 A = agg[base + ii];
                float w = dsl[ii] * dsl[ii];
                EDGE_BODY(g, A, w)
            }
        }
        // cross-wave reduce + global accumulate
        accs[wave][0][n0] = a00; accs[wave][0][n1] = a01;
        accs[wave][1][n0] = a10; accs[wave][1][n1] = a11;
        accs[wave][2][n0] = a20; accs[wave][2][n1] = a21;
        accs[wave][3][n0] = a30; accs[wave][3][n1] = a31;
        __syncthreads();
        if (t < DIM) {
#pragma unroll
            for (int r = 0; r < 4; ++r) {
                int g = gw + r;
                if (g <= ghi) {
                    float v = accs[0][r][t] + accs[1][r][t] + accs[2][r][t] + accs[3][r][t];
                    atomicAdd(&z[g * DIM + t], v);
                }
            }
        }
        __syncthreads();
    }
}

// ---------------- head ----------------

__global__ void k_bounds(const int* __restrict__ batch, float* __restrict__ cnts) {
    __shared__ int start[NG + 1];
    int t = threadIdx.x;
    if (t <= NG) {
        int lo = 0, hi = N_NODES;
        while (lo < hi) {
            int mid = (lo + hi) >> 1;
            if (batch[mid] < t) lo = mid + 1; else hi = mid;
        }
        start[t] = lo;
    }
    __syncthreads();
    if (t < NG) cnts[t] = (float)(start[t + 1] - start[t]);
}

__global__ void k_poolmix(const float* __restrict__ z, const float* __restrict__ W2,
                          const float* __restrict__ b2, const float* __restrict__ cnts,
                          float* __restrict__ embed) {
    int id = blockIdx.x * blockDim.x + threadIdx.x;
    if (id >= NG * DIM) return;
    int g = id >> 7, n = id & 127;
    float acc = 0.f;
#pragma unroll 4
    for (int k = 0; k < DIM; ++k) acc = fmaf(z[g * DIM + k], W2[k * DIM + n], acc);
    embed[id] = acc / fmaxf(cnts[g], 1.0f) + b2[n];
}

__global__ void k_final(const float* __restrict__ embed, const float* __restrict__ Wf,
                        const float* __restrict__ bf, float* __restrict__ out) {
    int id = blockIdx.x * blockDim.x + threadIdx.x;
    if (id >= NG * ACT) return;
    int g = id >> 9, a = id & 511;
    float acc = 0.f;
#pragma unroll 4
    for (int c = 0; c < DIM; ++c) acc = fmaf(embed[g * DIM + c], Wf[c * ACT + a], acc);
    out[id] = acc + bf[a];
}

// ---------------- launch ----------------

static inline size_t align256(size_t x) { return (x + 255) & ~(size_t)255; }

extern "C" void kernel_launch(void* const* d_in, const int* in_sizes, int n_in,
                              void* d_out, int out_size, void* d_ws, size_t ws_size,
                              hipStream_t stream) {
    const float* x  = (const float*)d_in[0];
    const int*   ei = (const int*)d_in[1];
    const int*   batch = (const int*)d_in[2];
    const float* W1 = (const float*)d_in[3];
    const float* b1 = (const float*)d_in[4];
    const float* W2 = (const float*)d_in[5];
    const float* b2 = (const float*)d_in[6];
    const float* Wf = (const float*)d_in[7];
    const float* bf = (const float*)d_in[8];
    float* out = (float*)d_out;

    const int* src = ei;
    const int* dst = ei + N_EDGES;

    char* ws = (char*)d_ws;
    size_t off = 0;
    int*   hist    = (int*)(ws + off);   off = align256(off + (size_t)NBLK_E * NBUK * 4);
    int*   colsum  = (int*)(ws + off);   off = align256(off + NBUK * 4);
    int*   off_d   = (int*)(ws + off);   off = align256(off + (NBUK + 1) * 4);
    int*   edata_d = (int*)(ws + off);   off = align256(off + (size_t)N_EDGES * 4);
    float* dis     = (float*)(ws + off); off = align256(off + N_NODES * 4);
    float4* xd     = (float4*)(ws + off); off = align256(off + (size_t)N_NODES * 16);
    float4* agg    = (float4*)(ws + off); off = align256(off + (size_t)N_NODES * 16);
    float* z       = (float*)(ws + off); off = align256(off + NG * DIM * 4);
    float* embed   = (float*)(ws + off); off = align256(off + NG * DIM * 4);
    float* cnts    = (float*)(ws + off); off = align256(off + NG * 4);

    hipMemsetAsync(z, 0, NG * DIM * 4, stream);

    k_histA<<<NBLK_E, 256, 0, stream>>>(dst, hist);
    k_bscanA<<<NBUK, 512, 0, stream>>>(hist, colsum);
    k_bscanB<<<1, 1024, 0, stream>>>(colsum, off_d);
    k_bscanC<<<(NBLK_E * NBUK + 255) / 256, 256, 0, stream>>>(hist, off_d);
    k_bfill<<<NBLK_E, 256, 0, stream>>>(src, dst, hist, edata_d);

    k_indeg<<<NBUK, 256, 0, stream>>>(edata_d, off_d, x, dis, xd);
    k_agg<<<NBUK, 256, 0, stream>>>(edata_d, off_d, xd, agg);
    k_zgemm<<<NBUK, 256, 0, stream>>>(agg, edata_d, off_d, batch, dis, W1, b1, z);

    k_bounds<<<1, 128, 0, stream>>>(batch, cnts);
    k_poolmix<<<(NG * DIM + 255) / 256, 256, 0, stream>>>(z, W2, b2, cnts, embed);
    k_final<<<(NG * ACT + 255) / 256, 256, 0, stream>>>(embed, Wf, bf, out);
}

// Round 11
// 278.970 us; speedup vs baseline: 1.1644x; 1.1644x over previous
//
#include <hip/hip_runtime.h>

#define N_NODES 100000
#define N_EDGES 1600000
#define DIM 128
#define ACT 512
#define NG 64
#define CHUNK 128
#define NBUK 782            // ceil(N_NODES/CHUNK)
#define NBUK2 (2 * NBUK)
#define EB 4096             // edges per partition block
#define NBLK_E 391          // ceil(N_EDGES/EB)

// ---------------- chunk-granular edge partition, both sides ----------------

__global__ __launch_bounds__(256) void k_hist(const int* __restrict__ src,
                                              const int* __restrict__ dst,
                                              int* __restrict__ hist) {
    __shared__ int lh[NBUK2];
    int t = threadIdx.x;
    for (int i = t; i < NBUK2; i += 256) lh[i] = 0;
    __syncthreads();
    int e0 = blockIdx.x * EB;
    int e1 = min(e0 + EB, N_EDGES);
    for (int i = e0 + t; i < e1; i += 256) {
        atomicAdd(&lh[dst[i] >> 7], 1);
        atomicAdd(&lh[NBUK + (src[i] >> 7)], 1);
    }
    __syncthreads();
    int* row = hist + (size_t)blockIdx.x * NBUK2;
    for (int i = t; i < NBUK2; i += 256) row[i] = lh[i];
}

// per-bucket column scan over blocks
__global__ __launch_bounds__(512) void k_bscanA(int* __restrict__ hist,
                                                int* __restrict__ colsum) {
    __shared__ int s[512];
    int b = blockIdx.x, t = threadIdx.x;
    int v = (t < NBLK_E) ? hist[(size_t)t * NBUK2 + b] : 0;
    s[t] = v;
    __syncthreads();
    for (int off = 1; off < 512; off <<= 1) {
        int add = (t >= off) ? s[t - off] : 0;
        __syncthreads();
        s[t] += add;
        __syncthreads();
    }
    if (t < NBLK_E) hist[(size_t)t * NBUK2 + b] = s[t] - v;
    if (t == 511) colsum[b] = s[511];
}

// scan bucket totals -> off_d, off_s
__global__ __launch_bounds__(1024) void k_bscanB(const int* __restrict__ colsum,
                                                 int* __restrict__ off_d,
                                                 int* __restrict__ off_s) {
    __shared__ int s[1024];
    int t = threadIdx.x;
    int v = (t < NBUK) ? colsum[t] : 0;
    s[t] = v;
    __syncthreads();
    for (int off = 1; off < 1024; off <<= 1) {
        int add = (t >= off) ? s[t - off] : 0;
        __syncthreads();
        s[t] += add;
        __syncthreads();
    }
    if (t < NBUK) off_d[t] = s[t] - v;
    if (t == 1023) off_d[NBUK] = s[1023];
    __syncthreads();
    int v2 = (t < NBUK) ? colsum[NBUK + t] : 0;
    s[t] = v2;
    __syncthreads();
    for (int off = 1; off < 1024; off <<= 1) {
        int add = (t >= off) ? s[t - off] : 0;
        __syncthreads();
        s[t] += add;
        __syncthreads();
    }
    if (t < NBUK) off_s[t] = s[t] - v2;
    if (t == 1023) off_s[NBUK] = s[1023];
}

__global__ void k_bscanC(int* __restrict__ hist, const int* __restrict__ off_d,
                         const int* __restrict__ off_s) {
    int id = blockIdx.x * blockDim.x + threadIdx.x;
    if (id >= NBLK_E * NBUK2) return;
    int b = id % NBUK2;
    hist[id] += (b < NBUK) ? off_d[b] : off_s[b - NBUK];
}

// dual fill. dst payload: (dlocal7<<17)|src17. src payload: (slocal7<<23)|(g6<<17)|dst17
__global__ __launch_bounds__(256) void k_bfill(const int* __restrict__ src,
                                               const int* __restrict__ dst,
                                               const int* __restrict__ batch,
                                               const int* __restrict__ hist,
                                               int* __restrict__ edata_d,
                                               int* __restrict__ edata_s) {
    __shared__ int cur[NBUK2];
    int t = threadIdx.x;
    const int* row = hist + (size_t)blockIdx.x * NBUK2;
    for (int i = t; i < NBUK2; i += 256) cur[i] = row[i];
    __syncthreads();
    int e0 = blockIdx.x * EB;
    int e1 = min(e0 + EB, N_EDGES);
    for (int i = e0 + t; i < e1; i += 256) {
        int s = src[i], d = dst[i];
        int g = batch[d];
        int pd = atomicAdd(&cur[d >> 7], 1);
        edata_d[pd] = ((d & 127) << 17) | s;
        int ps = atomicAdd(&cur[NBUK + (s >> 7)], 1);
        edata_s[ps] = ((s & 127) << 23) | (g << 17) | d;
    }
}

// ---------------- per-chunk in-degree -> dis, xd ----------------

__global__ __launch_bounds__(256) void k_indeg(const int* __restrict__ edata_d,
                                               const int* __restrict__ off_d,
                                               const float* __restrict__ x,
                                               float* __restrict__ dis,
                                               float4* __restrict__ xd) {
    __shared__ int cnt[CHUNK];
    int t = threadIdx.x;
    int b = blockIdx.x;
    if (t < CHUNK) cnt[t] = 0;
    __syncthreads();
    int e0 = off_d[b], e1 = off_d[b + 1];
    for (int i = e0 + t; i < e1; i += 256) atomicAdd(&cnt[edata_d[i] >> 17], 1);
    __syncthreads();
    if (t < CHUNK) {
        int node = b * CHUNK + t;
        if (node < N_NODES) {
            float d = rsqrtf((float)(cnt[t] + 1));
            dis[node] = d;
            float4 p;
            p.x = x[node * 3 + 0] * d;
            p.y = x[node * 3 + 1] * d;
            p.z = x[node * 3 + 2] * d;
            p.w = d;
            xd[node] = p;
        }
    }
}

// ---------------- layer-1 aggregation per dst chunk; agg.w = dis ----------------

__global__ __launch_bounds__(256) void k_agg(const int* __restrict__ edata_d,
                                             const int* __restrict__ off_d,
                                             const float4* __restrict__ xd,
                                             float4* __restrict__ agg) {
    __shared__ float ax[CHUNK], ay[CHUNK], az[CHUNK];
    int t = threadIdx.x;
    int b = blockIdx.x;
    if (t < CHUNK) { ax[t] = 0.f; ay[t] = 0.f; az[t] = 0.f; }
    __syncthreads();
    int e0 = off_d[b], e1 = off_d[b + 1];
    for (int i = e0 + t; i < e1; i += 256) {
        int p = edata_d[i];
        int dl = p >> 17;
        int s = p & 0x1FFFF;
        float4 y = xd[s];
        atomicAdd(&ax[dl], y.x);
        atomicAdd(&ay[dl], y.y);
        atomicAdd(&az[dl], y.z);
    }
    __syncthreads();
    if (t < CHUNK) {
        int node = b * CHUNK + t;
        if (node < N_NODES) {
            float4 self = xd[node];
            float d = self.w;
            float4 o;
            o.x = (ax[t] + self.x) * d;
            o.y = (ay[t] + self.y) * d;
            o.z = (az[t] + self.z) * d;
            o.w = d;
            agg[node] = o;
        }
    }
}

// ---------------- fused coefficient build + z contraction (src chunks) ----------------
// zpart[b][g][n] = sum_{s in chunk b} c[s][g] * u_s[n],
// c[s][g] = dis_s * sum_{d in out(s), batch[d]=g} dis_d  +  [batch_s=g]*dis_s^2
// u_s[n] = relu(agg_s @ W1[:,n] + b1[n]) recomputed per node (amortized over edges).
__global__ __launch_bounds__(256) void k_zgemm(const float4* __restrict__ agg,
                                               const int* __restrict__ edata_s,
                                               const int* __restrict__ off_s,
                                               const int* __restrict__ batch,
                                               const float* __restrict__ dis,
                                               const float* __restrict__ W1,
                                               const float* __restrict__ b1,
                                               float* __restrict__ zpart) {
    __shared__ float ctile[CHUNK][NG];   // 32 KB
    __shared__ float dsl[CHUNK];
    __shared__ float4 ags[CHUNK];
    int t = threadIdx.x;
    int a = t >> 5;      // 0..7 -> owns g in {8a..8a+7}
    int b = t & 31;      // 0..31 -> owns n in {b, b+32, b+64, b+96}
    int blk = blockIdx.x;
    int base = blk * CHUNK;

    float w1r0[4], w1r1[4], w1r2[4], b1r[4];
#pragma unroll
    for (int j = 0; j < 4; ++j) {
        int n = b + j * 32;
        w1r0[j] = W1[0 * DIM + n];
        w1r1[j] = W1[1 * DIM + n];
        w1r2[j] = W1[2 * DIM + n];
        b1r[j]  = b1[n];
    }
    for (int idx = t; idx < CHUNK * NG; idx += 256) ((float*)ctile)[idx] = 0.f;
    if (t < CHUNK) {
        int s = base + t;
        if (s < N_NODES) {
            dsl[t] = dis[s];
            ags[t] = agg[s];
        } else {
            dsl[t] = 0.f;
            ags[t] = (float4){0.f, 0.f, 0.f, 0.f};
        }
    }
    __syncthreads();
    // edge phase: g comes packed in the payload; only dis[d] is gathered (L2)
    int e0 = off_s[blk], e1 = off_s[blk + 1];
    for (int i = e0 + t; i < e1; i += 256) {
        int p = edata_s[i];
        int sl = p >> 23;
        int g = (p >> 17) & 63;
        int d = p & 0x1FFFF;
        atomicAdd(&ctile[sl][g], dsl[sl] * dis[d]);
    }
    if (t < CHUNK) {
        int s = base + t;
        if (s < N_NODES) atomicAdd(&ctile[t][batch[s]], dsl[t] * dsl[t]);
    }
    __syncthreads();
    // dense compute phase: u per node amortized over all 64 groups
    float acc[8][4];
#pragma unroll
    for (int gi = 0; gi < 8; ++gi)
#pragma unroll
        for (int j = 0; j < 4; ++j) acc[gi][j] = 0.f;
    for (int nn = 0; nn < CHUNK; ++nn) {
        float4 ag = ags[nn];
        float u[4];
#pragma unroll
        for (int j = 0; j < 4; ++j) {
            float h = fmaf(ag.x, w1r0[j], fmaf(ag.y, w1r1[j], fmaf(ag.z, w1r2[j], b1r[j])));
            u[j] = fmaxf(h, 0.f);
        }
        const float4* cr = (const float4*)&ctile[nn][a * 8];
        float4 c0 = cr[0];
        float4 c1 = cr[1];
        float cv[8] = {c0.x, c0.y, c0.z, c0.w, c1.x, c1.y, c1.z, c1.w};
#pragma unroll
        for (int gi = 0; gi < 8; ++gi) {
#pragma unroll
            for (int j = 0; j < 4; ++j)
                acc[gi][j] = fmaf(cv[gi], u[j], acc[gi][j]);
        }
    }
    float* zp = zpart + (size_t)blk * (NG * DIM);
#pragma unroll
    for (int gi = 0; gi < 8; ++gi) {
        int g = a * 8 + gi;
#pragma unroll
        for (int j = 0; j < 4; ++j) {
            int n = b + j * 32;
            zp[g * DIM + n] = acc[gi][j];
        }
    }
}

// z[i] = sum_b zpart[b][i]
__global__ void k_zred(const float* __restrict__ zpart, float* __restrict__ z) {
    int i = blockIdx.x * blockDim.x + threadIdx.x;
    if (i >= NG * DIM) return;
    float acc = 0.f;
    for (int b = 0; b < NBUK; ++b) acc += zpart[(size_t)b * (NG * DIM) + i];
    z[i] = acc;
}

// ---------------- head ----------------

__global__ void k_bounds(const int* __restrict__ batch, float* __restrict__ cnts) {
    __shared__ int start[NG + 1];
    int t = threadIdx.x;
    if (t <= NG) {
        int lo = 0, hi = N_NODES;
        while (lo < hi) {
            int mid = (lo + hi) >> 1;
            if (batch[mid] < t) lo = mid + 1; else hi = mid;
        }
        start[t] = lo;
    }
    __syncthreads();
    if (t < NG) cnts[t] = (float)(start[t + 1] - start[t]);
}

__global__ void k_poolmix(const float* __restrict__ z, const float* __restrict__ W2,
                          const float* __restrict__ b2, const float* __restrict__ cnts,
                          float* __restrict__ embed) {
    int id = blockIdx.x * blockDim.x + threadIdx.x;
    if (id >= NG * DIM) return;
    int g = id >> 7, n = id & 127;
    float acc = 0.f;
#pragma unroll 4
    for (int k = 0; k < DIM; ++k) acc = fmaf(z[g * DIM + k], W2[k * DIM + n], acc);
    embed[id] = acc / fmaxf(cnts[g], 1.0f) + b2[n];
}

__global__ void k_final(const float* __restrict__ embed, const float* __restrict__ Wf,
                        const float* __restrict__ bf, float* __restrict__ out) {
    int id = blockIdx.x * blockDim.x + threadIdx.x;
    if (id >= NG * ACT) return;
    int g = id >> 9, a = id & 511;
    float acc = 0.f;
#pragma unroll 4
    for (int c = 0; c < DIM; ++c) acc = fmaf(embed[g * DIM + c], Wf[c * ACT + a], acc);
    out[id] = acc + bf[a];
}

// ---------------- launch ----------------

static inline size_t align256(size_t x) { return (x + 255) & ~(size_t)255; }

extern "C" void kernel_launch(void* const* d_in, const int* in_sizes, int n_in,
                              void* d_out, int out_size, void* d_ws, size_t ws_size,
                              hipStream_t stream) {
    const float* x  = (const float*)d_in[0];
    const int*   ei = (const int*)d_in[1];
    const int*   batch = (const int*)d_in[2];
    const float* W1 = (const float*)d_in[3];
    const float* b1 = (const float*)d_in[4];
    const float* W2 = (const float*)d_in[5];
    const float* b2 = (const float*)d_in[6];
    const float* Wf = (const float*)d_in[7];
    const float* bf = (const float*)d_in[8];
    float* out = (float*)d_out;

    const int* src = ei;
    const int* dst = ei + N_EDGES;

    char* ws = (char*)d_ws;
    size_t off = 0;
    int*   hist    = (int*)(ws + off);   off = align256(off + (size_t)NBLK_E * NBUK2 * 4);
    int*   colsum  = (int*)(ws + off);   off = align256(off + NBUK2 * 4);
    int*   off_d   = (int*)(ws + off);   off = align256(off + (NBUK + 1) * 4);
    int*   off_s   = (int*)(ws + off);   off = align256(off + (NBUK + 1) * 4);
    int*   edata_d = (int*)(ws + off);   off = align256(off + (size_t)N_EDGES * 4);
    int*   edata_s = (int*)(ws + off);   off = align256(off + (size_t)N_EDGES * 4);
    float* dis     = (float*)(ws + off); off = align256(off + N_NODES * 4);
    float4* xd     = (float4*)(ws + off); off = align256(off + (size_t)N_NODES * 16);
    float4* agg    = (float4*)(ws + off); off = align256(off + (size_t)N_NODES * 16);
    float* zpart   = (float*)(ws + off); off = align256(off + (size_t)NBUK * NG * DIM * 4);
    float* z       = (float*)(ws + off); off = align256(off + NG * DIM * 4);
    float* embed   = (float*)(ws + off); off = align256(off + NG * DIM * 4);
    float* cnts    = (float*)(ws + off); off = align256(off + NG * 4);

    k_hist<<<NBLK_E, 256, 0, stream>>>(src, dst, hist);
    k_bscanA<<<NBUK2, 512, 0, stream>>>(hist, colsum);
    k_bscanB<<<1, 1024, 0, stream>>>(colsum, off_d, off_s);
    k_bscanC<<<(NBLK_E * NBUK2 + 255) / 256, 256, 0, stream>>>(hist, off_d, off_s);
    k_bfill<<<NBLK_E, 256, 0, stream>>>(src, dst, batch, hist, edata_d, edata_s);

    k_indeg<<<NBUK, 256, 0, stream>>>(edata_d, off_d, x, dis, xd);
    k_agg<<<NBUK, 256, 0, stream>>>(edata_d, off_d, xd, agg);
    k_zgemm<<<NBUK, 256, 0, stream>>>(agg, edata_s, off_s, batch, dis, W1, b1, zpart);
    k_zred<<<(NG * DIM + 255) / 256, 256, 0, stream>>>(zpart, z);

    k_bounds<<<1, 128, 0, stream>>>(batch, cnts);
    k_poolmix<<<(NG * DIM + 255) / 256, 256, 0, stream>>>(z, W2, b2, cnts, embed);
    k_final<<<(NG * ACT + 255) / 256, 256, 0, stream>>>(embed, Wf, bf, out);
}